// Round 1
// baseline (566.355 us; speedup 1.0000x reference)
//
#include <hip/hip_runtime.h>

// Problem constants (match reference):
//   RES = [64,128,256,512,1024], NF=8 channels, NC=2 staggered cells, P=1e6
//   out: (P, 40) float32, row-major: out[p*40 + lvl*8 + c]

__global__ __launch_bounds__(256) void transform_kernel(
    const float* __restrict__ src,  // (2, 8, HW)
    float* __restrict__ dst,        // (2, HW, 8)
    int HW) {
  int i = blockIdx.x * blockDim.x + threadIdx.x;  // over 2*HW
  if (i >= 2 * HW) return;
  int cell = i / HW;
  int pix  = i - cell * HW;
  const float* s = src + (size_t)cell * 8u * (size_t)HW + (size_t)pix;
  float4 lo, hi;
  lo.x = s[0 * (size_t)HW];
  lo.y = s[1 * (size_t)HW];
  lo.z = s[2 * (size_t)HW];
  lo.w = s[3 * (size_t)HW];
  hi.x = s[4 * (size_t)HW];
  hi.y = s[5 * (size_t)HW];
  hi.z = s[6 * (size_t)HW];
  hi.w = s[7 * (size_t)HW];
  float4* d = (float4*)(dst + (size_t)i * 8u);
  d[0] = lo;
  d[1] = hi;
}

// ---- fast path: channel-last layout (nc, H, W, 8) ----
template <int W>
__device__ __forceinline__ void sample_level_fast(
    const float* __restrict__ t, float xv, float yv, float* __restrict__ o) {
  float acc[8];
#pragma unroll
  for (int i = 0; i < 8; ++i) acc[i] = 0.0f;

  float xn = xv * 2.0f - 1.0f;
  float yn = yv * 2.0f - 1.0f;
#pragma unroll
  for (int cell = 0; cell < 2; ++cell) {
    const float off = 0.5f * (float)cell;
    float ix = (xn + 1.0f) * 0.5f * (float)(W - 1) + off;
    float iy = (yn + 1.0f) * 0.5f * (float)(W - 1) + off;
    float x0f = floorf(ix), y0f = floorf(iy);
    float wx = ix - x0f, wy = iy - y0f;
    int x0 = (int)x0f;
    x0 = x0 < 0 ? 0 : (x0 > W - 1 ? W - 1 : x0);
    int y0 = (int)y0f;
    y0 = y0 < 0 ? 0 : (y0 > W - 1 ? W - 1 : y0);
    int x1 = x0 + 1 > W - 1 ? W - 1 : x0 + 1;
    int y1 = y0 + 1 > W - 1 ? W - 1 : y0 + 1;

    const float* b = t + (size_t)cell * (size_t)W * (size_t)W * 8u;
    const float4* p00 = (const float4*)(b + ((size_t)y0 * W + x0) * 8u);
    const float4* p01 = (const float4*)(b + ((size_t)y0 * W + x1) * 8u);
    const float4* p10 = (const float4*)(b + ((size_t)y1 * W + x0) * 8u);
    const float4* p11 = (const float4*)(b + ((size_t)y1 * W + x1) * 8u);
    float4 nwa = p00[0], nwb = p00[1];
    float4 nea = p01[0], neb = p01[1];
    float4 swa = p10[0], swb = p10[1];
    float4 sea = p11[0], seb = p11[1];

    float w00 = (1.0f - wx) * (1.0f - wy);
    float w01 = wx * (1.0f - wy);
    float w10 = (1.0f - wx) * wy;
    float w11 = wx * wy;

    float nw[8] = {nwa.x, nwa.y, nwa.z, nwa.w, nwb.x, nwb.y, nwb.z, nwb.w};
    float ne[8] = {nea.x, nea.y, nea.z, nea.w, neb.x, neb.y, neb.z, neb.w};
    float sw[8] = {swa.x, swa.y, swa.z, swa.w, swb.x, swb.y, swb.z, swb.w};
    float se[8] = {sea.x, sea.y, sea.z, sea.w, seb.x, seb.y, seb.z, seb.w};
#pragma unroll
    for (int c = 0; c < 8; ++c) {
      acc[c] += nw[c] * w00 + ne[c] * w01 + sw[c] * w10 + se[c] * w11;
    }
  }
#pragma unroll
  for (int i = 0; i < 8; ++i) o[i] = acc[i];
}

__global__ __launch_bounds__(256) void sample_kernel_fast(
    const float* __restrict__ x, const float* __restrict__ y,
    const float* __restrict__ t0, const float* __restrict__ t1,
    const float* __restrict__ t2, const float* __restrict__ t3,
    const float* __restrict__ t4, float* __restrict__ out, int P) {
  int p = blockIdx.x * blockDim.x + threadIdx.x;
  if (p >= P) return;
  float xv = x[p];
  float yv = y[p];
  float o[8];
  float* orow = out + (size_t)p * 40u;

  sample_level_fast<64>(t0, xv, yv, o);
  ((float4*)(orow + 0))[0] = make_float4(o[0], o[1], o[2], o[3]);
  ((float4*)(orow + 0))[1] = make_float4(o[4], o[5], o[6], o[7]);
  sample_level_fast<128>(t1, xv, yv, o);
  ((float4*)(orow + 8))[0] = make_float4(o[0], o[1], o[2], o[3]);
  ((float4*)(orow + 8))[1] = make_float4(o[4], o[5], o[6], o[7]);
  sample_level_fast<256>(t2, xv, yv, o);
  ((float4*)(orow + 16))[0] = make_float4(o[0], o[1], o[2], o[3]);
  ((float4*)(orow + 16))[1] = make_float4(o[4], o[5], o[6], o[7]);
  sample_level_fast<512>(t3, xv, yv, o);
  ((float4*)(orow + 24))[0] = make_float4(o[0], o[1], o[2], o[3]);
  ((float4*)(orow + 24))[1] = make_float4(o[4], o[5], o[6], o[7]);
  sample_level_fast<1024>(t4, xv, yv, o);
  ((float4*)(orow + 32))[0] = make_float4(o[0], o[1], o[2], o[3]);
  ((float4*)(orow + 32))[1] = make_float4(o[4], o[5], o[6], o[7]);
}

// ---- fallback path: native layout (nc, 8, H, W) ----
template <int W>
__device__ __forceinline__ void sample_level_direct(
    const float* __restrict__ t, float xv, float yv, float* __restrict__ o) {
  float acc[8];
#pragma unroll
  for (int i = 0; i < 8; ++i) acc[i] = 0.0f;

  float xn = xv * 2.0f - 1.0f;
  float yn = yv * 2.0f - 1.0f;
#pragma unroll
  for (int cell = 0; cell < 2; ++cell) {
    const float off = 0.5f * (float)cell;
    float ix = (xn + 1.0f) * 0.5f * (float)(W - 1) + off;
    float iy = (yn + 1.0f) * 0.5f * (float)(W - 1) + off;
    float x0f = floorf(ix), y0f = floorf(iy);
    float wx = ix - x0f, wy = iy - y0f;
    int x0 = (int)x0f;
    x0 = x0 < 0 ? 0 : (x0 > W - 1 ? W - 1 : x0);
    int y0 = (int)y0f;
    y0 = y0 < 0 ? 0 : (y0 > W - 1 ? W - 1 : y0);
    int x1 = x0 + 1 > W - 1 ? W - 1 : x0 + 1;
    int y1 = y0 + 1 > W - 1 ? W - 1 : y0 + 1;

    float w00 = (1.0f - wx) * (1.0f - wy);
    float w01 = wx * (1.0f - wy);
    float w10 = (1.0f - wx) * wy;
    float w11 = wx * wy;

    const float* b = t + (size_t)cell * 8u * (size_t)W * (size_t)W;
    size_t i00 = (size_t)y0 * W + x0;
    size_t i01 = (size_t)y0 * W + x1;
    size_t i10 = (size_t)y1 * W + x0;
    size_t i11 = (size_t)y1 * W + x1;
#pragma unroll
    for (int c = 0; c < 8; ++c) {
      const float* pc = b + (size_t)c * (size_t)W * (size_t)W;
      acc[c] += pc[i00] * w00 + pc[i01] * w01 + pc[i10] * w10 + pc[i11] * w11;
    }
  }
#pragma unroll
  for (int i = 0; i < 8; ++i) o[i] = acc[i];
}

__global__ __launch_bounds__(256) void sample_kernel_direct(
    const float* __restrict__ x, const float* __restrict__ y,
    const float* __restrict__ t0, const float* __restrict__ t1,
    const float* __restrict__ t2, const float* __restrict__ t3,
    const float* __restrict__ t4, float* __restrict__ out, int P) {
  int p = blockIdx.x * blockDim.x + threadIdx.x;
  if (p >= P) return;
  float xv = x[p];
  float yv = y[p];
  float o[8];
  float* orow = out + (size_t)p * 40u;

  sample_level_direct<64>(t0, xv, yv, o);
#pragma unroll
  for (int i = 0; i < 8; ++i) orow[0 + i] = o[i];
  sample_level_direct<128>(t1, xv, yv, o);
#pragma unroll
  for (int i = 0; i < 8; ++i) orow[8 + i] = o[i];
  sample_level_direct<256>(t2, xv, yv, o);
#pragma unroll
  for (int i = 0; i < 8; ++i) orow[16 + i] = o[i];
  sample_level_direct<512>(t3, xv, yv, o);
#pragma unroll
  for (int i = 0; i < 8; ++i) orow[24 + i] = o[i];
  sample_level_direct<1024>(t4, xv, yv, o);
#pragma unroll
  for (int i = 0; i < 8; ++i) orow[32 + i] = o[i];
}

extern "C" void kernel_launch(void* const* d_in, const int* in_sizes, int n_in,
                              void* d_out, int out_size, void* d_ws, size_t ws_size,
                              hipStream_t stream) {
  const float* x = (const float*)d_in[0];
  const float* y = (const float*)d_in[1];
  const float* tabs[5] = {(const float*)d_in[2], (const float*)d_in[3],
                          (const float*)d_in[4], (const float*)d_in[5],
                          (const float*)d_in[6]};
  float* out = (float*)d_out;
  const int P = in_sizes[0];
  const int res[5] = {64, 128, 256, 512, 1024};

  // workspace layout: transformed tables, channel-last, back-to-back (floats)
  size_t offs[5];
  size_t total_f = 0;
  for (int l = 0; l < 5; ++l) {
    offs[l] = total_f;
    total_f += 2ull * 8ull * (size_t)res[l] * (size_t)res[l];
  }

  if (ws_size >= total_f * sizeof(float)) {
    float* ws = (float*)d_ws;
    for (int l = 0; l < 5; ++l) {
      int HW = res[l] * res[l];
      int n = 2 * HW;
      transform_kernel<<<(n + 255) / 256, 256, 0, stream>>>(tabs[l], ws + offs[l], HW);
    }
    sample_kernel_fast<<<(P + 255) / 256, 256, 0, stream>>>(
        x, y, ws + offs[0], ws + offs[1], ws + offs[2], ws + offs[3], ws + offs[4],
        out, P);
  } else {
    sample_kernel_direct<<<(P + 255) / 256, 256, 0, stream>>>(
        x, y, tabs[0], tabs[1], tabs[2], tabs[3], tabs[4], out, P);
  }
}

// Round 2
// 337.842 us; speedup vs baseline: 1.6764x; 1.6764x over previous
//
#include <hip/hip_runtime.h>

// Problem constants (match reference):
//   RES = [64,128,256,512,1024], NF=8 channels, NC=2 staggered cells, P=1e6
//   out: (P, 40) float32, row-major: out[p*40 + lvl*8 + c]
//
// Strategy: pre-transform each table from (nc, 8, H, W) fp32 to
// (nc, H, W, 8) bf16 in d_ws. Then each bilinear corner is a single
// 16-byte (uint4) gather of all 8 channels.

typedef __attribute__((ext_vector_type(8))) unsigned short ushort8v;

__device__ __forceinline__ unsigned short f2bf(float f) {
  union { float f; unsigned u; } c; c.f = f;
  unsigned u = c.u;
  u += 0x7FFFu + ((u >> 16) & 1u);   // round-to-nearest-even
  return (unsigned short)(u >> 16);
}

__global__ __launch_bounds__(256) void transform_bf16_kernel(
    const float* __restrict__ src,        // (2, 8, HW) fp32
    unsigned short* __restrict__ dst,     // (2, HW, 8) bf16
    int HW) {
  int i = blockIdx.x * blockDim.x + threadIdx.x;  // over 2*HW pixels
  if (i >= 2 * HW) return;
  int cell = i / HW;
  int pix  = i - cell * HW;
  const float* s = src + (size_t)cell * 8u * (size_t)HW + (size_t)pix;
  ushort8v v;
#pragma unroll
  for (int c = 0; c < 8; ++c) v[c] = f2bf(s[(size_t)c * (size_t)HW]);
  ((ushort8v*)dst)[i] = v;
}

__device__ __forceinline__ void fma8(uint4 v, float w, float* __restrict__ acc) {
  acc[0] = fmaf(__uint_as_float(v.x << 16), w, acc[0]);
  acc[1] = fmaf(__uint_as_float(v.x & 0xFFFF0000u), w, acc[1]);
  acc[2] = fmaf(__uint_as_float(v.y << 16), w, acc[2]);
  acc[3] = fmaf(__uint_as_float(v.y & 0xFFFF0000u), w, acc[3]);
  acc[4] = fmaf(__uint_as_float(v.z << 16), w, acc[4]);
  acc[5] = fmaf(__uint_as_float(v.z & 0xFFFF0000u), w, acc[5]);
  acc[6] = fmaf(__uint_as_float(v.w << 16), w, acc[6]);
  acc[7] = fmaf(__uint_as_float(v.w & 0xFFFF0000u), w, acc[7]);
}

// t: (2, W, W, 8) bf16 channel-last. One uint4 per pixel.
template <int W>
__device__ __forceinline__ void sample_level(const unsigned short* __restrict__ t,
                                             float xn, float yn,
                                             float* __restrict__ o) {
  const uint4* tp = (const uint4*)t;
  int xa[2], xb[2], ya[2], yb[2];
  float wx[2], wy[2];
#pragma unroll
  for (int cell = 0; cell < 2; ++cell) {
    const float off = 0.5f * (float)cell;
    float ix = (xn + 1.0f) * 0.5f * (float)(W - 1) + off;
    float iy = (yn + 1.0f) * 0.5f * (float)(W - 1) + off;
    float xf = floorf(ix), yf = floorf(iy);
    wx[cell] = ix - xf;
    wy[cell] = iy - yf;
    int xi = (int)xf; xi = xi < 0 ? 0 : (xi > W - 1 ? W - 1 : xi);
    int yi = (int)yf; yi = yi < 0 ? 0 : (yi > W - 1 ? W - 1 : yi);
    xa[cell] = xi; xb[cell] = xi + 1 > W - 1 ? W - 1 : xi + 1;
    ya[cell] = yi; yb[cell] = yi + 1 > W - 1 ? W - 1 : yi + 1;
  }
  // Issue all 8 corner gathers before any unpack/FMA.
  uint4 v[8];
#pragma unroll
  for (int cell = 0; cell < 2; ++cell) {
    const uint4* b = tp + (size_t)cell * (size_t)W * (size_t)W;
    v[cell * 4 + 0] = b[(size_t)ya[cell] * W + xa[cell]];
    v[cell * 4 + 1] = b[(size_t)ya[cell] * W + xb[cell]];
    v[cell * 4 + 2] = b[(size_t)yb[cell] * W + xa[cell]];
    v[cell * 4 + 3] = b[(size_t)yb[cell] * W + xb[cell]];
  }
  float acc[8];
#pragma unroll
  for (int i = 0; i < 8; ++i) acc[i] = 0.0f;
#pragma unroll
  for (int cell = 0; cell < 2; ++cell) {
    float w00 = (1.0f - wx[cell]) * (1.0f - wy[cell]);
    float w01 = wx[cell] * (1.0f - wy[cell]);
    float w10 = (1.0f - wx[cell]) * wy[cell];
    float w11 = wx[cell] * wy[cell];
    fma8(v[cell * 4 + 0], w00, acc);
    fma8(v[cell * 4 + 1], w01, acc);
    fma8(v[cell * 4 + 2], w10, acc);
    fma8(v[cell * 4 + 3], w11, acc);
  }
#pragma unroll
  for (int i = 0; i < 8; ++i) o[i] = acc[i];
}

__global__ __launch_bounds__(256, 4) void sample_kernel_bf16(
    const float* __restrict__ x, const float* __restrict__ y,
    const unsigned short* __restrict__ t0, const unsigned short* __restrict__ t1,
    const unsigned short* __restrict__ t2, const unsigned short* __restrict__ t3,
    const unsigned short* __restrict__ t4, float* __restrict__ out, int P) {
  int p = blockIdx.x * blockDim.x + threadIdx.x;
  if (p >= P) return;
  float xn = x[p] * 2.0f - 1.0f;
  float yn = y[p] * 2.0f - 1.0f;
  float o[8];
  float* orow = out + (size_t)p * 40u;

  sample_level<64>(t0, xn, yn, o);
  ((float4*)(orow + 0))[0] = make_float4(o[0], o[1], o[2], o[3]);
  ((float4*)(orow + 0))[1] = make_float4(o[4], o[5], o[6], o[7]);
  sample_level<128>(t1, xn, yn, o);
  ((float4*)(orow + 8))[0] = make_float4(o[0], o[1], o[2], o[3]);
  ((float4*)(orow + 8))[1] = make_float4(o[4], o[5], o[6], o[7]);
  sample_level<256>(t2, xn, yn, o);
  ((float4*)(orow + 16))[0] = make_float4(o[0], o[1], o[2], o[3]);
  ((float4*)(orow + 16))[1] = make_float4(o[4], o[5], o[6], o[7]);
  sample_level<512>(t3, xn, yn, o);
  ((float4*)(orow + 24))[0] = make_float4(o[0], o[1], o[2], o[3]);
  ((float4*)(orow + 24))[1] = make_float4(o[4], o[5], o[6], o[7]);
  sample_level<1024>(t4, xn, yn, o);
  ((float4*)(orow + 32))[0] = make_float4(o[0], o[1], o[2], o[3]);
  ((float4*)(orow + 32))[1] = make_float4(o[4], o[5], o[6], o[7]);
}

// ---- fallback path: native layout (nc, 8, H, W), fp32 direct ----
template <int W>
__device__ __forceinline__ void sample_level_direct(
    const float* __restrict__ t, float xv, float yv, float* __restrict__ o) {
  float acc[8];
#pragma unroll
  for (int i = 0; i < 8; ++i) acc[i] = 0.0f;
  float xn = xv * 2.0f - 1.0f;
  float yn = yv * 2.0f - 1.0f;
#pragma unroll
  for (int cell = 0; cell < 2; ++cell) {
    const float off = 0.5f * (float)cell;
    float ix = (xn + 1.0f) * 0.5f * (float)(W - 1) + off;
    float iy = (yn + 1.0f) * 0.5f * (float)(W - 1) + off;
    float x0f = floorf(ix), y0f = floorf(iy);
    float wx = ix - x0f, wy = iy - y0f;
    int x0 = (int)x0f; x0 = x0 < 0 ? 0 : (x0 > W - 1 ? W - 1 : x0);
    int y0 = (int)y0f; y0 = y0 < 0 ? 0 : (y0 > W - 1 ? W - 1 : y0);
    int x1 = x0 + 1 > W - 1 ? W - 1 : x0 + 1;
    int y1 = y0 + 1 > W - 1 ? W - 1 : y0 + 1;
    float w00 = (1.0f - wx) * (1.0f - wy);
    float w01 = wx * (1.0f - wy);
    float w10 = (1.0f - wx) * wy;
    float w11 = wx * wy;
    const float* b = t + (size_t)cell * 8u * (size_t)W * (size_t)W;
    size_t i00 = (size_t)y0 * W + x0;
    size_t i01 = (size_t)y0 * W + x1;
    size_t i10 = (size_t)y1 * W + x0;
    size_t i11 = (size_t)y1 * W + x1;
#pragma unroll
    for (int c = 0; c < 8; ++c) {
      const float* pc = b + (size_t)c * (size_t)W * (size_t)W;
      acc[c] += pc[i00] * w00 + pc[i01] * w01 + pc[i10] * w10 + pc[i11] * w11;
    }
  }
#pragma unroll
  for (int i = 0; i < 8; ++i) o[i] = acc[i];
}

__global__ __launch_bounds__(256) void sample_kernel_direct(
    const float* __restrict__ x, const float* __restrict__ y,
    const float* __restrict__ t0, const float* __restrict__ t1,
    const float* __restrict__ t2, const float* __restrict__ t3,
    const float* __restrict__ t4, float* __restrict__ out, int P) {
  int p = blockIdx.x * blockDim.x + threadIdx.x;
  if (p >= P) return;
  float xv = x[p];
  float yv = y[p];
  float o[8];
  float* orow = out + (size_t)p * 40u;
  sample_level_direct<64>(t0, xv, yv, o);
#pragma unroll
  for (int i = 0; i < 8; ++i) orow[0 + i] = o[i];
  sample_level_direct<128>(t1, xv, yv, o);
#pragma unroll
  for (int i = 0; i < 8; ++i) orow[8 + i] = o[i];
  sample_level_direct<256>(t2, xv, yv, o);
#pragma unroll
  for (int i = 0; i < 8; ++i) orow[16 + i] = o[i];
  sample_level_direct<512>(t3, xv, yv, o);
#pragma unroll
  for (int i = 0; i < 8; ++i) orow[24 + i] = o[i];
  sample_level_direct<1024>(t4, xv, yv, o);
#pragma unroll
  for (int i = 0; i < 8; ++i) orow[32 + i] = o[i];
}

extern "C" void kernel_launch(void* const* d_in, const int* in_sizes, int n_in,
                              void* d_out, int out_size, void* d_ws, size_t ws_size,
                              hipStream_t stream) {
  const float* x = (const float*)d_in[0];
  const float* y = (const float*)d_in[1];
  const float* tabs[5] = {(const float*)d_in[2], (const float*)d_in[3],
                          (const float*)d_in[4], (const float*)d_in[5],
                          (const float*)d_in[6]};
  float* out = (float*)d_out;
  const int P = in_sizes[0];
  const int res[5] = {64, 128, 256, 512, 1024};

  // workspace layout: bf16 channel-last tables, back-to-back (ushort units)
  size_t offs[5];
  size_t total_e = 0;
  for (int l = 0; l < 5; ++l) {
    offs[l] = total_e;
    total_e += 2ull * 8ull * (size_t)res[l] * (size_t)res[l];
  }

  if (ws_size >= total_e * sizeof(unsigned short)) {
    unsigned short* ws = (unsigned short*)d_ws;
    for (int l = 0; l < 5; ++l) {
      int HW = res[l] * res[l];
      int n = 2 * HW;
      transform_bf16_kernel<<<(n + 255) / 256, 256, 0, stream>>>(tabs[l], ws + offs[l], HW);
    }
    sample_kernel_bf16<<<(P + 255) / 256, 256, 0, stream>>>(
        x, y, ws + offs[0], ws + offs[1], ws + offs[2], ws + offs[3], ws + offs[4],
        out, P);
  } else {
    sample_kernel_direct<<<(P + 255) / 256, 256, 0, stream>>>(
        x, y, tabs[0], tabs[1], tabs[2], tabs[3], tabs[4], out, P);
  }
}